// Round 1
// baseline (299.233 us; speedup 1.0000x reference)
//
#include <hip/hip_runtime.h>
#include <hip/hip_bf16.h>

// Word2Vec NCE loss:
//   B=16384 batch, C=10 context, K=5 negatives/context, V=400000, D=300 (fp32)
// loss = -mean_b[ mean_c logsig(ctx_bc . tgt_b) + mean_c sum_k logsig(-neg_bck . tgt_b) ]

#define D_DIM 300
#define C_DIM 10
#define NEG_DIM 50   // C*K
#define ROWS 60      // C + C*K

__device__ __forceinline__ float log_sigmoid(float x) {
    // stable: min(x,0) - log1p(exp(-|x|))
    return fminf(x, 0.f) - log1pf(__expf(-fabsf(x)));
}

__global__ __launch_bounds__(256) void w2v_loss_partial(
    const int*   __restrict__ target,
    const int*   __restrict__ context,
    const int*   __restrict__ negs,
    const float* __restrict__ emb_in,
    const float* __restrict__ emb_out,
    float*       __restrict__ partial)
{
    const int b    = blockIdx.x;
    const int tid  = threadIdx.x;
    const int lane = tid & 63;
    const int wave = tid >> 6;   // 0..3

    __shared__ float s_tgt[D_DIM];
    __shared__ float s_acc[4];

    // stage target embedding row in LDS
    const size_t trow = (size_t)target[b] * D_DIM;
    for (int i = tid; i < D_DIM; i += 256) s_tgt[i] = emb_in[trow + i];
    __syncthreads();

    float acc = 0.f;
    // 60 rows split across 4 waves
    for (int r = wave; r < ROWS; r += 4) {
        int idx; float sign;
        if (r < C_DIM) { idx = context[b * C_DIM + r];        sign =  1.f; }
        else           { idx = negs[b * NEG_DIM + (r - C_DIM)]; sign = -1.f; }

        const float* row = emb_out + (size_t)idx * D_DIM;
        float dot = 0.f;
        #pragma unroll
        for (int j = lane; j < D_DIM; j += 64)
            dot += row[j] * s_tgt[j];

        // 64-lane butterfly reduce
        #pragma unroll
        for (int off = 32; off > 0; off >>= 1)
            dot += __shfl_xor(dot, off, 64);

        acc += log_sigmoid(sign * dot);
    }

    if (lane == 0) s_acc[wave] = acc;
    __syncthreads();
    if (tid == 0) partial[b] = s_acc[0] + s_acc[1] + s_acc[2] + s_acc[3];
}

__global__ __launch_bounds__(256) void w2v_loss_reduce(
    const float* __restrict__ partial,
    float*       __restrict__ out,
    int n, float inv_scale)
{
    __shared__ float s[256];
    float acc = 0.f;
    for (int i = threadIdx.x; i < n; i += 256) acc += partial[i];
    s[threadIdx.x] = acc;
    __syncthreads();
    #pragma unroll
    for (int off = 128; off > 0; off >>= 1) {
        if (threadIdx.x < off) s[threadIdx.x] += s[threadIdx.x + off];
        __syncthreads();
    }
    if (threadIdx.x == 0) out[0] = -s[0] * inv_scale;
}

extern "C" void kernel_launch(void* const* d_in, const int* in_sizes, int n_in,
                              void* d_out, int out_size, void* d_ws, size_t ws_size,
                              hipStream_t stream) {
    const int*   target  = (const int*)  d_in[0];
    const int*   context = (const int*)  d_in[1];
    const int*   negs    = (const int*)  d_in[2];
    const float* emb_in  = (const float*)d_in[3];
    const float* emb_out = (const float*)d_in[4];
    float*       out     = (float*)d_out;

    const int B = in_sizes[0];              // 16384
    float* partial = (float*)d_ws;          // B floats

    w2v_loss_partial<<<B, 256, 0, stream>>>(target, context, negs,
                                            emb_in, emb_out, partial);
    const float inv_scale = 1.0f / ((float)B * (float)C_DIM);
    w2v_loss_reduce<<<1, 256, 0, stream>>>(partial, out, B, inv_scale);
}

// Round 2
// 210.568 us; speedup vs baseline: 1.4211x; 1.4211x over previous
//
#include <hip/hip_runtime.h>
#include <hip/hip_bf16.h>

// Word2Vec NCE loss:
//   B=16384 batch, C=10 context, K=5 negatives/context, V=400000, D=300 (fp32)
// loss = -mean_b[ mean_c logsig(ctx_bc . tgt_b) + mean_c sum_k logsig(-neg_bck . tgt_b) ]

#define D_DIM 300
#define D4    75     // float4 per row (300/4)
#define C_DIM 10
#define NEG_DIM 50   // C*K
#define ROWS 60      // C + C*K

__device__ __forceinline__ float log_sigmoid_fast(float x) {
    // min(x,0) - log(1+exp(-|x|)); fast exp/log (v_exp_f32/v_log_f32).
    // For large |x|, exp(-|x|) underflows against 1.0 -> error <= ~4e-8/term.
    float e = __expf(-fabsf(x));
    return fminf(x, 0.f) - __logf(1.f + e);
}

__global__ __launch_bounds__(256) void w2v_loss_partial(
    const int*   __restrict__ target,
    const int*   __restrict__ context,
    const int*   __restrict__ negs,
    const float* __restrict__ emb_in,
    const float* __restrict__ emb_out,
    float*       __restrict__ partial)
{
    const int b    = blockIdx.x;
    const int tid  = threadIdx.x;
    const int lane = tid & 63;
    const int wave = tid >> 6;   // 0..3

    __shared__ int   s_idx[ROWS + 4]; // 60 indices (pad for alignment)
    __shared__ float s_acc[4];

    // stage the 60 gather indices once
    if (tid < C_DIM)       s_idx[tid] = context[b * C_DIM + tid];
    else if (tid < ROWS)   s_idx[tid] = negs[b * NEG_DIM + (tid - C_DIM)];
    __syncthreads();

    // target row fragment in registers: lane j holds float4 j and j+64
    const float4* trow =
        reinterpret_cast<const float4*>(emb_in + (size_t)target[b] * D_DIM);
    float4 ta = trow[lane];
    float4 tb = make_float4(0.f, 0.f, 0.f, 0.f);
    if (lane < D4 - 64) tb = trow[64 + lane];   // lanes 0..10

    float acc = 0.f;
    #pragma unroll 3
    for (int rr = 0; rr < ROWS / 4; ++rr) {     // 15 rows per wave
        const int r   = wave + rr * 4;
        const int idx = s_idx[r];
        const float4* row =
            reinterpret_cast<const float4*>(emb_out + (size_t)idx * D_DIM);
        float4 ra = row[lane];
        float4 rb = make_float4(0.f, 0.f, 0.f, 0.f);
        if (lane < D4 - 64) rb = row[64 + lane];

        float dot = ra.x * ta.x + ra.y * ta.y + ra.z * ta.z + ra.w * ta.w
                  + rb.x * tb.x + rb.y * tb.y + rb.z * tb.z + rb.w * tb.w;

        // 64-lane butterfly reduce
        #pragma unroll
        for (int off = 32; off > 0; off >>= 1)
            dot += __shfl_xor(dot, off, 64);

        const float x = (r < C_DIM) ? dot : -dot;
        acc += log_sigmoid_fast(x);
    }

    if (lane == 0) s_acc[wave] = acc;
    __syncthreads();
    if (tid == 0) partial[b] = s_acc[0] + s_acc[1] + s_acc[2] + s_acc[3];
}

__global__ __launch_bounds__(256) void w2v_loss_reduce(
    const float* __restrict__ partial,
    float*       __restrict__ out,
    int n, float inv_scale)
{
    __shared__ float s[256];
    float acc = 0.f;
    for (int i = threadIdx.x; i < n; i += 256) acc += partial[i];
    s[threadIdx.x] = acc;
    __syncthreads();
    #pragma unroll
    for (int off = 128; off > 0; off >>= 1) {
        if (threadIdx.x < off) s[threadIdx.x] += s[threadIdx.x + off];
        __syncthreads();
    }
    if (threadIdx.x == 0) out[0] = -s[0] * inv_scale;
}

extern "C" void kernel_launch(void* const* d_in, const int* in_sizes, int n_in,
                              void* d_out, int out_size, void* d_ws, size_t ws_size,
                              hipStream_t stream) {
    const int*   target  = (const int*)  d_in[0];
    const int*   context = (const int*)  d_in[1];
    const int*   negs    = (const int*)  d_in[2];
    const float* emb_in  = (const float*)d_in[3];
    const float* emb_out = (const float*)d_in[4];
    float*       out     = (float*)d_out;

    const int B = in_sizes[0];              // 16384
    float* partial = (float*)d_ws;          // B floats

    w2v_loss_partial<<<B, 256, 0, stream>>>(target, context, negs,
                                            emb_in, emb_out, partial);
    const float inv_scale = 1.0f / ((float)B * (float)C_DIM);
    w2v_loss_reduce<<<1, 256, 0, stream>>>(partial, out, B, inv_scale);
}

// Round 3
// 209.945 us; speedup vs baseline: 1.4253x; 1.0030x over previous
//
#include <hip/hip_runtime.h>
#include <hip/hip_bf16.h>

// Word2Vec NCE loss:
//   B=16384 batch, C=10 context, K=5 negatives/context, V=400000, D=300 (fp32)
// loss = -mean_b[ mean_c logsig(ctx_bc . tgt_b) + mean_c sum_k logsig(-neg_bck . tgt_b) ]
//
// Structure: 1 wave per batch element (256-thr block = 4 b's). 60 rows in 15
// groups of 4; batched butterfly reduce (10 shfl per 4 rows) leaves each
// 16-lane group holding one row's dot -> one logsig instruction covers 4 rows.

#define D_DIM 300
#define D4    75     // float4 per row
#define C_DIM 10
#define NEG_DIM 50   // C*K
#define ROWS 60      // C + C*K

__device__ __forceinline__ float log_sigmoid_fast(float x) {
    float e = __expf(-fabsf(x));
    return fminf(x, 0.f) - __logf(1.f + e);
}

__global__ __launch_bounds__(256) void w2v_loss_partial(
    const int*   __restrict__ target,
    const int*   __restrict__ context,
    const int*   __restrict__ negs,
    const float* __restrict__ emb_in,
    const float* __restrict__ emb_out,
    float*       __restrict__ partial)
{
    const int tid  = threadIdx.x;
    const int lane = tid & 63;
    const int wave = tid >> 6;
    const int b    = blockIdx.x * 4 + wave;

    // lane r (<60) holds gather index of row r
    int v_idx = 0;
    if (lane < C_DIM)      v_idx = context[b * C_DIM + lane];
    else if (lane < ROWS)  v_idx = negs[b * NEG_DIM + (lane - C_DIM)];

    // target row in registers: lane j holds float4 j and (64+j)
    const float4* trow =
        reinterpret_cast<const float4*>(emb_in + (size_t)target[b] * D_DIM);
    const bool tail = lane < (D4 - 64);   // lanes 0..10
    float4 ta = trow[lane];
    float4 tb = make_float4(0.f, 0.f, 0.f, 0.f);
    if (tail) tb = trow[64 + lane];

    float acc = 0.f;
    #pragma unroll 3
    for (int g = 0; g < ROWS / 4; ++g) {
        float d[4];
        #pragma unroll
        for (int i = 0; i < 4; ++i) {
            const int r = g * 4 + i;
            const int sidx = __builtin_amdgcn_readlane(v_idx, r); // uniform
            const float4* row =
                reinterpret_cast<const float4*>(emb_out + (size_t)sidx * D_DIM);
            float4 ra = row[lane];
            float4 rb = make_float4(0.f, 0.f, 0.f, 0.f);
            if (tail) rb = row[64 + lane];
            d[i] = ra.x * ta.x + ra.y * ta.y + ra.z * ta.z + ra.w * ta.w
                 + rb.x * tb.x + rb.y * tb.y + rb.z * tb.z + rb.w * tb.w;
        }

        // batched 4-row butterfly: each 16-lane group ends with one row's sum
        #pragma unroll
        for (int i = 0; i < 4; ++i) d[i] += __shfl_xor(d[i], 32, 64);
        const bool hi32 = (lane & 32) != 0;
        float p = hi32 ? d[1] : d[0];
        float q = hi32 ? d[3] : d[2];
        p += __shfl_xor(p, 16, 64);
        q += __shfl_xor(q, 16, 64);
        float v = (lane & 16) ? q : p;
        v += __shfl_xor(v, 8, 64);
        v += __shfl_xor(v, 4, 64);
        v += __shfl_xor(v, 2, 64);
        v += __shfl_xor(v, 1, 64);

        // 16-lane group (lane>>4) holds row g*4 + perm, perm = {0,2,1,3}
        const int gq  = lane >> 4;
        const int rid = g * 4 + (((gq & 1) << 1) | (gq >> 1));
        const float x = (rid < C_DIM) ? v : -v;
        acc += log_sigmoid_fast(x);
    }

    // combine the 4 group-accumulators (each replicated 16x)
    acc += __shfl_xor(acc, 16, 64);
    acc += __shfl_xor(acc, 32, 64);
    if (lane == 0) partial[b] = acc;
}

__global__ __launch_bounds__(256) void w2v_loss_reduce(
    const float* __restrict__ partial,
    float*       __restrict__ out,
    int n, float inv_scale)
{
    __shared__ float s[256];
    float acc = 0.f;
    for (int i = threadIdx.x; i < n; i += 256) acc += partial[i];
    s[threadIdx.x] = acc;
    __syncthreads();
    #pragma unroll
    for (int off = 128; off > 0; off >>= 1) {
        if (threadIdx.x < off) s[threadIdx.x] += s[threadIdx.x + off];
        __syncthreads();
    }
    if (threadIdx.x == 0) out[0] = -s[0] * inv_scale;
}

extern "C" void kernel_launch(void* const* d_in, const int* in_sizes, int n_in,
                              void* d_out, int out_size, void* d_ws, size_t ws_size,
                              hipStream_t stream) {
    const int*   target  = (const int*)  d_in[0];
    const int*   context = (const int*)  d_in[1];
    const int*   negs    = (const int*)  d_in[2];
    const float* emb_in  = (const float*)d_in[3];
    const float* emb_out = (const float*)d_in[4];
    float*       out     = (float*)d_out;

    const int B = in_sizes[0];              // 16384
    float* partial = (float*)d_ws;          // B floats

    w2v_loss_partial<<<B / 4, 256, 0, stream>>>(target, context, negs,
                                                emb_in, emb_out, partial);
    const float inv_scale = 1.0f / ((float)B * (float)C_DIM);
    w2v_loss_reduce<<<1, 256, 0, stream>>>(partial, out, B, inv_scale);
}